// Round 1
// baseline (18477.261 us; speedup 1.0000x reference)
//
#include <hip/hip_runtime.h>
#include <math.h>

#define H   512
#define S   64
#define T   128
#define NB  128
#define L   512

// workspace layout (float elements)
#define OFF_ENC   0u               // enc_out [N][L][H]  33,554,432
#define OFF_Q     33554432u        // q_all   [T][N][H]   8,388,608
#define OFF_ATTN  41943040u        // attn    [T][N][H]   8,388,608
#define OFF_WPE   50331648u        // packed enc Whh (float4 view) 786,432 fl
#define OFF_WPD   51118080u        // packed dec Whh|Wih 1,572,864 fl
#define OFF_M4    52690944u        // M packed [k4][s][4] 65,536 fl
#define OFF_C     52756480u        // c[64]

// output layout (float elements)
#define OUT_V  0
#define OUT_HN 1048576
#define OUT_W  1114112

__device__ __forceinline__ float sigmoidf_(float x){ return 1.0f/(1.0f+expf(-x)); }

// ---------------- prep: pack W[j][k] -> WP[k4][j][4] (k4-major, j coalesced) ----
__global__ void pack_w_kernel(float4* __restrict__ dst, const float* __restrict__ srcA,
                              const float* __restrict__ srcB, int k4A, int k4tot){
  int idx = blockIdx.x*256 + threadIdx.x;
  if (idx >= k4tot*1536) return;
  int k4 = idx / 1536, j = idx % 1536;
  const float* s = (k4 < k4A) ? (srcA + (size_t)j*H + k4*4)
                              : (srcB + (size_t)j*H + (k4-k4A)*4);
  dst[idx] = make_float4(s[0], s[1], s[2], s[3]);
}

// ---------------- prep: M[k][s] = sum_o affW[o][k]*fcW[s][o]; c[s] ----------------
__global__ void prep_m_kernel(float* __restrict__ M4, float* __restrict__ c,
                              const float* __restrict__ aW, const float* __restrict__ aB,
                              const float* __restrict__ fcW, const float* __restrict__ fcB){
  int idx = blockIdx.x*256 + threadIdx.x;   // 65536 = 1024k x 64s
  int k = idx >> 6, s = idx & 63;
  float acc = 0.f;
  for (int o = 0; o < H; ++o) acc += aW[(size_t)o*1024 + k] * fcW[(size_t)s*H + o];
  int k4 = k >> 2, kk = k & 3;
  M4[(size_t)(k4*64 + s)*4 + kk] = acc;
  if (idx < 64){
    float a2 = 0.f;
    for (int o = 0; o < H; ++o) a2 += aB[o] * fcW[(size_t)idx*H + o];
    c[idx] = a2 + fcB[idx];
  }
}

// ---------------- encoder GRU step t: h(t) = GRU(x_t, h(t-1)) -> enc[n][t][:] ----
__global__ __launch_bounds__(256) void enc_step_kernel(
    float* __restrict__ enc, const float* __restrict__ x,
    const float* __restrict__ Wih, const float* __restrict__ bih,
    const float* __restrict__ bhh, const float4* __restrict__ WP, int t){
  __shared__ __align__(16) float hs[8][H];
  int tid = threadIdx.x;
  int n0 = blockIdx.x * 8;
  int jh = blockIdx.y * 32 + (tid & 31);
  int n_l = tid >> 5;
  if (t == 0){
    for (int i = tid; i < 8*H/4; i += 256) ((float4*)hs)[i] = make_float4(0,0,0,0);
  } else {
    for (int i = tid; i < 8*H/4; i += 256){
      int r = i >> 7, kv = i & 127;
      ((float4*)&hs[r][0])[kv] = *(const float4*)&enc[((size_t)(n0+r)*L + (t-1))*H + kv*4];
    }
  }
  __syncthreads();
  float ar=0.f, az=0.f, an=0.f;
  #pragma unroll 4
  for (int k4 = 0; k4 < 128; ++k4){
    float4 h4 = ((const float4*)&hs[n_l][0])[k4];
    float4 wr = WP[k4*1536 + jh];
    float4 wz = WP[k4*1536 + 512 + jh];
    float4 wn = WP[k4*1536 + 1024 + jh];
    ar += h4.x*wr.x + h4.y*wr.y + h4.z*wr.z + h4.w*wr.w;
    az += h4.x*wz.x + h4.y*wz.y + h4.z*wz.z + h4.w*wz.w;
    an += h4.x*wn.x + h4.y*wn.y + h4.z*wn.z + h4.w*wn.w;
  }
  int n = n0 + n_l;
  float x0 = x[(size_t)n*1024 + t], x1 = x[(size_t)n*1024 + 512 + t];
  float ir  = x0*Wih[jh*2]        + x1*Wih[jh*2+1]        + bih[jh];
  float iz  = x0*Wih[(512+jh)*2]  + x1*Wih[(512+jh)*2+1]  + bih[512+jh];
  float inn = x0*Wih[(1024+jh)*2] + x1*Wih[(1024+jh)*2+1] + bih[1024+jh];
  float r = sigmoidf_(ir + ar + bhh[jh]);
  float z = sigmoidf_(iz + az + bhh[512+jh]);
  float nn = tanhf(inn + r*(an + bhh[1024+jh]));
  float hp = hs[n_l][jh];
  enc[((size_t)n*L + t)*H + jh] = (1.f - z)*nn + z*hp;
}

// ---------------- decoder GRU step t: q(t) = GRU(emb[tok_t], q(t-1)) ----------------
__global__ __launch_bounds__(256) void dec_step_kernel(
    const float* __restrict__ enc, float* __restrict__ q_all,
    const int* __restrict__ tgt, const float* __restrict__ emb,
    const float* __restrict__ bih, const float* __restrict__ bhh,
    const float4* __restrict__ WP, float* __restrict__ hn_out, int t){
  __shared__ __align__(16) float hs[8][H];
  __shared__ __align__(16) float es[8][H];
  int tid = threadIdx.x;
  int n0 = blockIdx.x * 8;
  int jh = blockIdx.y * 32 + (tid & 31);
  int n_l = tid >> 5;
  for (int i = tid; i < 8*H/4; i += 256){
    int r = i >> 7, kv = i & 127;
    const float* hsrc = (t == 0) ? &enc[((size_t)(n0+r)*L + (L-1))*H]
                                 : &q_all[(size_t)(t-1)*NB*H + (size_t)(n0+r)*H];
    ((float4*)&hs[r][0])[kv] = *(const float4*)&hsrc[kv*4];
    int tok = (t == 0) ? 0 : tgt[(n0+r)*T + (t-1)];
    ((float4*)&es[r][0])[kv] = *(const float4*)&emb[(size_t)tok*H + kv*4];
  }
  __syncthreads();
  float ar=0.f, az=0.f, ainn=0.f, ahn=0.f;
  #pragma unroll 4
  for (int k4 = 0; k4 < 128; ++k4){
    float4 h4 = ((const float4*)&hs[n_l][0])[k4];
    float4 wr = WP[k4*1536 + jh];
    float4 wz = WP[k4*1536 + 512 + jh];
    float4 wn = WP[k4*1536 + 1024 + jh];
    ar  += h4.x*wr.x + h4.y*wr.y + h4.z*wr.z + h4.w*wr.w;
    az  += h4.x*wz.x + h4.y*wz.y + h4.z*wz.z + h4.w*wz.w;
    ahn += h4.x*wn.x + h4.y*wn.y + h4.z*wn.z + h4.w*wn.w;
  }
  #pragma unroll 4
  for (int k4 = 0; k4 < 128; ++k4){
    float4 e4 = ((const float4*)&es[n_l][0])[k4];
    float4 wr = WP[(128+k4)*1536 + jh];
    float4 wz = WP[(128+k4)*1536 + 512 + jh];
    float4 wn = WP[(128+k4)*1536 + 1024 + jh];
    ar   += e4.x*wr.x + e4.y*wr.y + e4.z*wr.z + e4.w*wr.w;
    az   += e4.x*wz.x + e4.y*wz.y + e4.z*wz.z + e4.w*wz.w;
    ainn += e4.x*wn.x + e4.y*wn.y + e4.z*wn.z + e4.w*wn.w;
  }
  float r = sigmoidf_(ar + bih[jh] + bhh[jh]);
  float z = sigmoidf_(az + bih[512+jh] + bhh[512+jh]);
  float nn = tanhf(ainn + bih[1024+jh] + r*(ahn + bhh[1024+jh]));
  int n = n0 + n_l;
  float hp = hs[n_l][jh];
  float q = (1.f - z)*nn + z*hp;
  q_all[(size_t)t*NB*H + (size_t)n*H + jh] = q;
  if (t == T-1) hn_out[(size_t)n*H + jh] = q;
}

// ---------------- batched scores: s[n][t][l] = q[t][n][:] . enc[n][l][:] ------------
__global__ __launch_bounds__(256) void scores_kernel(
    const float* __restrict__ enc, const float* __restrict__ q_all,
    float* __restrict__ wout){
  int t0 = blockIdx.x * 16, l0 = blockIdx.y * 64, n = blockIdx.z;
  int tid = threadIdx.x;
  __shared__ __align__(16) float A[16][33];   // q[t][k-chunk]
  __shared__ __align__(16) float B[32][68];   // enc chunk transposed: B[k][l]
  int t_l = tid >> 4, l_g = tid & 15;
  float4 acc = make_float4(0,0,0,0);
  for (int kc = 0; kc < 16; ++kc){
    __syncthreads();
    for (int e = tid; e < 512; e += 256){
      int r = e >> 5, k = e & 31;
      A[r][k] = q_all[(size_t)(t0+r)*NB*H + (size_t)n*H + kc*32 + k];
    }
    for (int e = tid; e < 2048; e += 256){
      int l = e >> 5, k = e & 31;
      B[k][l] = enc[((size_t)n*L + l0 + l)*H + kc*32 + k];
    }
    __syncthreads();
    #pragma unroll
    for (int kk = 0; kk < 32; ++kk){
      float a = A[t_l][kk];
      float4 b = *(const float4*)&B[kk][l_g*4];
      acc.x += a*b.x; acc.y += a*b.y; acc.z += a*b.z; acc.w += a*b.w;
    }
  }
  *(float4*)&wout[(size_t)n*T*L + (size_t)(t0+t_l)*L + l0 + l_g*4] = acc;
}

// ---------------- softmax rows of all_w in place (one wave per (n,t)) --------------
__global__ __launch_bounds__(64) void softmax_kernel(float* __restrict__ w){
  float* p = w + (size_t)blockIdx.x * L;
  int lane = threadIdx.x;
  float4 v0 = *(float4*)&p[lane*8];
  float4 v1 = *(float4*)&p[lane*8+4];
  float m = fmaxf(fmaxf(fmaxf(v0.x,v0.y),fmaxf(v0.z,v0.w)),
                  fmaxf(fmaxf(v1.x,v1.y),fmaxf(v1.z,v1.w)));
  for (int off = 32; off; off >>= 1) m = fmaxf(m, __shfl_xor(m, off));
  v0.x = expf(v0.x-m); v0.y = expf(v0.y-m); v0.z = expf(v0.z-m); v0.w = expf(v0.w-m);
  v1.x = expf(v1.x-m); v1.y = expf(v1.y-m); v1.z = expf(v1.z-m); v1.w = expf(v1.w-m);
  float s = v0.x+v0.y+v0.z+v0.w+v1.x+v1.y+v1.z+v1.w;
  for (int off = 32; off; off >>= 1) s += __shfl_xor(s, off);
  float inv = 1.f/s;
  v0.x*=inv; v0.y*=inv; v0.z*=inv; v0.w*=inv;
  v1.x*=inv; v1.y*=inv; v1.z*=inv; v1.w*=inv;
  *(float4*)&p[lane*8] = v0;
  *(float4*)&p[lane*8+4] = v1;
}

// ---------------- batched attn: a[t][n][h] = sum_l w[n][t][l] * enc[n][l][h] -------
__global__ __launch_bounds__(256) void attn_kernel(
    const float* __restrict__ enc, const float* __restrict__ w_in,
    float* __restrict__ attn_all){
  int t0 = blockIdx.x * 16, h0 = blockIdx.y * 64, n = blockIdx.z;
  int tid = threadIdx.x;
  __shared__ __align__(16) float A[16][33];   // w[t][l-chunk]
  __shared__ __align__(16) float B[32][64];   // enc[l][h-chunk]
  int t_l = tid >> 4, h_g = tid & 15;
  float4 acc = make_float4(0,0,0,0);
  for (int lc = 0; lc < 16; ++lc){
    __syncthreads();
    for (int e = tid; e < 512; e += 256){
      int r = e >> 5, ll = e & 31;
      A[r][ll] = w_in[(size_t)n*T*L + (size_t)(t0+r)*L + lc*32 + ll];
    }
    for (int e = tid; e < 2048; e += 256){
      int ll = e >> 6, h = e & 63;
      B[ll][h] = enc[((size_t)n*L + lc*32 + ll)*H + h0 + h];
    }
    __syncthreads();
    #pragma unroll
    for (int ll = 0; ll < 32; ++ll){
      float a = A[t_l][ll];
      float4 b = *(const float4*)&B[ll][h_g*4];
      acc.x += a*b.x; acc.y += a*b.y; acc.z += a*b.z; acc.w += a*b.w;
    }
  }
  *(float4*)&attn_all[(size_t)(t0+t_l)*NB*H + (size_t)n*H + h0 + h_g*4] = acc;
}

// ---------------- output head: v[n][t][s] = c[s] + [q|attn] . M[:,s] ----------------
__global__ __launch_bounds__(256) void out_kernel(
    const float* __restrict__ q_all, const float* __restrict__ attn_all,
    const float4* __restrict__ M4, const float* __restrict__ c,
    float* __restrict__ vout){
  __shared__ __align__(16) float cat[4][1024];
  int tid = threadIdx.x;
  int row0 = blockIdx.x * 4;
  for (int e = tid; e < 4096; e += 256){
    int r = e >> 10, k = e & 1023;
    int row = row0 + r;
    int n = row >> 7, t = row & 127;
    cat[r][k] = (k < 512) ? q_all[(size_t)t*NB*H + (size_t)n*H + k]
                          : attn_all[(size_t)t*NB*H + (size_t)n*H + (k-512)];
  }
  __syncthreads();
  int r_l = tid >> 6, s = tid & 63;
  int row = row0 + r_l;
  int n = row >> 7, t = row & 127;
  float acc = c[s];
  #pragma unroll 4
  for (int k4 = 0; k4 < 256; ++k4){
    float4 cv = ((const float4*)&cat[r_l][0])[k4];
    float4 m = M4[k4*64 + s];
    acc += cv.x*m.x + cv.y*m.y + cv.z*m.z + cv.w*m.w;
  }
  vout[(size_t)n*T*S + (size_t)t*S + s] = acc;
}

extern "C" void kernel_launch(void* const* d_in, const int* in_sizes, int n_in,
                              void* d_out, int out_size, void* d_ws, size_t ws_size,
                              hipStream_t stream) {
  const float* x       = (const float*)d_in[0];
  const int*   target  = (const int*)d_in[1];
  const float* enc_Wih = (const float*)d_in[2];
  const float* enc_Whh = (const float*)d_in[3];
  const float* enc_bih = (const float*)d_in[4];
  const float* enc_bhh = (const float*)d_in[5];
  const float* dec_Wih = (const float*)d_in[6];
  const float* dec_Whh = (const float*)d_in[7];
  const float* dec_bih = (const float*)d_in[8];
  const float* dec_bhh = (const float*)d_in[9];
  const float* emb     = (const float*)d_in[10];
  const float* affW    = (const float*)d_in[11];
  const float* affB    = (const float*)d_in[12];
  const float* fcW     = (const float*)d_in[13];
  const float* fcB     = (const float*)d_in[14];

  float* ws      = (float*)d_ws;
  float* enc     = ws + OFF_ENC;
  float* q_all   = ws + OFF_Q;
  float* attn_al = ws + OFF_ATTN;
  float4* WPe    = (float4*)(ws + OFF_WPE);
  float4* WPd    = (float4*)(ws + OFF_WPD);
  float* M4f     = ws + OFF_M4;
  float* cb      = ws + OFF_C;

  float* vout   = (float*)d_out + OUT_V;
  float* hn_out = (float*)d_out + OUT_HN;
  float* w_all  = (float*)d_out + OUT_W;

  pack_w_kernel<<<768, 256, 0, stream>>>(WPe, enc_Whh, enc_Whh, 128, 128);
  pack_w_kernel<<<1536, 256, 0, stream>>>(WPd, dec_Whh, dec_Wih, 128, 256);
  prep_m_kernel<<<256, 256, 0, stream>>>(M4f, cb, affW, affB, fcW, fcB);

  for (int t = 0; t < L; ++t)
    enc_step_kernel<<<dim3(16,16), 256, 0, stream>>>(enc, x, enc_Wih, enc_bih, enc_bhh, WPe, t);

  for (int t = 0; t < T; ++t)
    dec_step_kernel<<<dim3(16,16), 256, 0, stream>>>(enc, q_all, target, emb, dec_bih, dec_bhh, WPd, hn_out, t);

  scores_kernel<<<dim3(8,8,NB), 256, 0, stream>>>(enc, q_all, w_all);
  softmax_kernel<<<NB*T, 64, 0, stream>>>(w_all);
  attn_kernel<<<dim3(8,8,NB), 256, 0, stream>>>(enc, w_all, attn_al);
  out_kernel<<<NB*T/4, 256, 0, stream>>>(q_all, attn_al, (const float4*)M4f, cb, vout);
}